// Round 1
// baseline (65.376 us; speedup 1.0000x reference)
//
#include <hip/hip_runtime.h>

// DSSIM loss: y_pred, y_true [8,3,512,512] fp32 -> scalar mean DSSIM.
// Per pixel: 3x3 window (zero-padded) x 3 channels = 27 elems.
// Stats via 5 raw sums; unbiased var (ddof=1); covar biased (mean of prod - prod of means).

#define N_IMG 8
#define C_CH 3
#define H_DIM 512
#define W_DIM 512
#define PXT 4                    // pixels per thread along W
#define WQ (W_DIM / PXT)         // 128 thread-columns per row
#define TOTAL_THREADS (N_IMG * H_DIM * WQ)   // 524288
#define BLOCK 256

__global__ __launch_bounds__(BLOCK) void dssim_kernel(
        const float* __restrict__ yp,
        const float* __restrict__ yt,
        float* __restrict__ out) {
    const int tid = blockIdx.x * BLOCK + threadIdx.x;
    const int wq = tid % WQ;
    const int h  = (tid / WQ) % H_DIM;
    const int n  = tid / (WQ * H_DIM);

    const int w0 = wq * PXT;

    // column accumulators: 6 input columns cover the 4 output windows
    float cT[6]  = {0.f,0.f,0.f,0.f,0.f,0.f};
    float cP[6]  = {0.f,0.f,0.f,0.f,0.f,0.f};
    float cTT[6] = {0.f,0.f,0.f,0.f,0.f,0.f};
    float cPP[6] = {0.f,0.f,0.f,0.f,0.f,0.f};
    float cTP[6] = {0.f,0.f,0.f,0.f,0.f,0.f};

    #pragma unroll
    for (int c = 0; c < C_CH; ++c) {
        #pragma unroll
        for (int dy = -1; dy <= 1; ++dy) {
            const int hh = h + dy;
            if ((unsigned)hh >= (unsigned)H_DIM) continue;  // zero pad row
            const size_t base = ((size_t)((n * C_CH + c) * H_DIM + hh)) * W_DIM;
            #pragma unroll
            for (int j = 0; j < 6; ++j) {
                const int ww = w0 - 1 + j;
                const bool valid = ((unsigned)ww < (unsigned)W_DIM);
                const float t = valid ? yt[base + ww] : 0.f;
                const float p = valid ? yp[base + ww] : 0.f;
                cT[j]  += t;
                cP[j]  += p;
                cTT[j] = fmaf(t, t, cTT[j]);
                cPP[j] = fmaf(p, p, cPP[j]);
                cTP[j] = fmaf(t, p, cTP[j]);
            }
        }
    }

    const float C1f = 1.0e-4f;       // (0.01*1)^2
    const float C2f = 9.0e-4f;       // (0.03*1)^2
    const float inv_n = 1.f / 27.f;
    const float inv_v = 1.f / 26.f;

    float lsum = 0.f;
    #pragma unroll
    for (int k = 0; k < PXT; ++k) {
        const float st  = cT[k]  + cT[k+1]  + cT[k+2];
        const float sp  = cP[k]  + cP[k+1]  + cP[k+2];
        const float stt = cTT[k] + cTT[k+1] + cTT[k+2];
        const float spp = cPP[k] + cPP[k+1] + cPP[k+2];
        const float stp = cTP[k] + cTP[k+1] + cTP[k+2];

        const float ut = st * inv_n;
        const float up = sp * inv_n;
        const float vart = (stt - st * st * inv_n) * inv_v;
        const float varp = (spp - sp * sp * inv_n) * inv_v;
        const float cov  = stp * inv_n - ut * up;

        const float num = (2.f * ut * up + C1f) * (2.f * cov + C2f);
        const float den = (ut * ut + up * up + C1f) * (vart + varp + C2f);
        lsum += (1.f - num / den) * 0.5f;
    }

    // wave (64-lane) reduction
    #pragma unroll
    for (int off = 32; off > 0; off >>= 1)
        lsum += __shfl_down(lsum, off, 64);

    __shared__ float smem[BLOCK / 64];
    const int lane = threadIdx.x & 63;
    const int wid  = threadIdx.x >> 6;
    if (lane == 0) smem[wid] = lsum;
    __syncthreads();
    if (threadIdx.x == 0) {
        float s = 0.f;
        #pragma unroll
        for (int i = 0; i < BLOCK / 64; ++i) s += smem[i];
        atomicAdd(out, s * (1.f / (float)(N_IMG * H_DIM * W_DIM)));
    }
}

extern "C" void kernel_launch(void* const* d_in, const int* in_sizes, int n_in,
                              void* d_out, int out_size, void* d_ws, size_t ws_size,
                              hipStream_t stream) {
    const float* yp = (const float*)d_in[0];   // y_pred
    const float* yt = (const float*)d_in[1];   // y_true
    float* out = (float*)d_out;

    hipMemsetAsync(out, 0, sizeof(float) * (size_t)out_size, stream);

    const int grid = TOTAL_THREADS / BLOCK;    // 2048 blocks
    dssim_kernel<<<grid, BLOCK, 0, stream>>>(yp, yt, out);
}

// Round 2
// 33.940 us; speedup vs baseline: 1.9262x; 1.9262x over previous
//
#include <hip/hip_runtime.h>

// DSSIM loss: y_pred, y_true [8,3,512,512] fp32 -> scalar mean DSSIM.
// One wave = one full image row (64 lanes x 8 px = 512 cols).
// Per (c,dy): two aligned float4 loads per tensor; halo cols via shfl.

#define N_IMG 8
#define C_CH 3
#define H_DIM 512
#define W_DIM 512
#define PXT 8                    // pixels per thread along W
#define TOTAL_THREADS (N_IMG * H_DIM * 64)   // 262144
#define BLOCK 256

__global__ __launch_bounds__(BLOCK) void dssim_kernel(
        const float* __restrict__ yp,
        const float* __restrict__ yt,
        float* __restrict__ out) {
    const int tid  = blockIdx.x * BLOCK + threadIdx.x;
    const int lane = tid & 63;            // = wq: 64 lanes cover one row
    const int r    = tid >> 6;            // row id over [N*H]
    const int h    = r & (H_DIM - 1);
    const int n    = r >> 9;              // /512

    const int w0 = lane * PXT;

    // 10 input columns (w0-1 .. w0+8) cover the 8 output windows
    float cT[10], cP[10], cTT[10], cPP[10], cTP[10];
    #pragma unroll
    for (int j = 0; j < 10; ++j) { cT[j]=0.f; cP[j]=0.f; cTT[j]=0.f; cPP[j]=0.f; cTP[j]=0.f; }

    #pragma unroll
    for (int c = 0; c < C_CH; ++c) {
        #pragma unroll
        for (int dy = -1; dy <= 1; ++dy) {
            const int hh = h + dy;
            if ((unsigned)hh >= (unsigned)H_DIM) continue;  // zero-pad row (wave-uniform)
            const size_t base = ((size_t)((n * C_CH + c) * H_DIM + hh)) * W_DIM + w0;

            const float4 t0 = *reinterpret_cast<const float4*>(yt + base);
            const float4 t1 = *reinterpret_cast<const float4*>(yt + base + 4);
            const float4 p0 = *reinterpret_cast<const float4*>(yp + base);
            const float4 p1 = *reinterpret_cast<const float4*>(yp + base + 4);

            // halo: col w0-1 = prev lane's t1.w; col w0+8 = next lane's t0.x
            float tm = __shfl_up(t1.w, 1);   if (lane == 0)  tm = 0.f;
            float pm = __shfl_up(p1.w, 1);   if (lane == 0)  pm = 0.f;
            float tq = __shfl_down(t0.x, 1); if (lane == 63) tq = 0.f;
            float pq = __shfl_down(p0.x, 1); if (lane == 63) pq = 0.f;

            const float tv[10] = {tm, t0.x, t0.y, t0.z, t0.w, t1.x, t1.y, t1.z, t1.w, tq};
            const float pv[10] = {pm, p0.x, p0.y, p0.z, p0.w, p1.x, p1.y, p1.z, p1.w, pq};

            #pragma unroll
            for (int j = 0; j < 10; ++j) {
                const float t = tv[j], p = pv[j];
                cT[j]  += t;
                cP[j]  += p;
                cTT[j] = fmaf(t, t, cTT[j]);
                cPP[j] = fmaf(p, p, cPP[j]);
                cTP[j] = fmaf(t, p, cTP[j]);
            }
        }
    }

    const float C1f = 1.0e-4f;       // (0.01*1)^2
    const float C2f = 9.0e-4f;       // (0.03*1)^2
    const float inv_n = 1.f / 27.f;
    const float inv_v = 1.f / 26.f;

    float lsum = 0.f;
    #pragma unroll
    for (int k = 0; k < PXT; ++k) {
        const float st  = cT[k]  + cT[k+1]  + cT[k+2];
        const float sp  = cP[k]  + cP[k+1]  + cP[k+2];
        const float stt = cTT[k] + cTT[k+1] + cTT[k+2];
        const float spp = cPP[k] + cPP[k+1] + cPP[k+2];
        const float stp = cTP[k] + cTP[k+1] + cTP[k+2];

        const float ut = st * inv_n;
        const float up = sp * inv_n;
        const float vart = (stt - st * st * inv_n) * inv_v;
        const float varp = (spp - sp * sp * inv_n) * inv_v;
        const float cov  = stp * inv_n - ut * up;

        const float num = (2.f * ut * up + C1f) * (2.f * cov + C2f);
        const float den = (ut * ut + up * up + C1f) * (vart + varp + C2f);
        lsum += (1.f - num / den) * 0.5f;
    }

    // wave (64-lane) reduction
    #pragma unroll
    for (int off = 32; off > 0; off >>= 1)
        lsum += __shfl_down(lsum, off, 64);

    __shared__ float smem[BLOCK / 64];
    const int wl  = threadIdx.x & 63;
    const int wid = threadIdx.x >> 6;
    if (wl == 0) smem[wid] = lsum;
    __syncthreads();
    if (threadIdx.x == 0) {
        float s = 0.f;
        #pragma unroll
        for (int i = 0; i < BLOCK / 64; ++i) s += smem[i];
        atomicAdd(out, s * (1.f / (float)(N_IMG * H_DIM * W_DIM)));
    }
}

extern "C" void kernel_launch(void* const* d_in, const int* in_sizes, int n_in,
                              void* d_out, int out_size, void* d_ws, size_t ws_size,
                              hipStream_t stream) {
    const float* yp = (const float*)d_in[0];   // y_pred
    const float* yt = (const float*)d_in[1];   // y_true
    float* out = (float*)d_out;

    hipMemsetAsync(out, 0, sizeof(float) * (size_t)out_size, stream);

    const int grid = TOTAL_THREADS / BLOCK;    // 1024 blocks
    dssim_kernel<<<grid, BLOCK, 0, stream>>>(yp, yt, out);
}

// Round 3
// 33.574 us; speedup vs baseline: 1.9472x; 1.0109x over previous
//
#include <hip/hip_runtime.h>

// DSSIM loss: y_pred, y_true [8,3,512,512] fp32 -> scalar mean DSSIM.
// One wave = one full image row (64 lanes x 8 px = 512 cols).
// Lanes accumulate 5 column-sums for their 8 owned columns only;
// halo column sums come from ONE post-loop shfl of the accumulated sums
// (neighbor lane's col7/col0 sums), so loads have no DS dependency.

#define N_IMG 8
#define C_CH 3
#define H_DIM 512
#define W_DIM 512
#define PXT 8                    // pixels per thread along W
#define TOTAL_THREADS (N_IMG * H_DIM * 64)   // 262144
#define BLOCK 256

__global__ __launch_bounds__(BLOCK) void dssim_kernel(
        const float* __restrict__ yp,
        const float* __restrict__ yt,
        float* __restrict__ out) {
    const int tid  = blockIdx.x * BLOCK + threadIdx.x;
    const int lane = tid & 63;            // 64 lanes cover one row
    const int r    = tid >> 6;            // row id over [N*H]
    const int h    = r & (H_DIM - 1);
    const int n    = r >> 9;              // /512

    const int w0 = lane * PXT;

    // accumulators for the 8 owned columns
    float aT[8], aP[8], aTT[8], aPP[8], aTP[8];
    #pragma unroll
    for (int j = 0; j < 8; ++j) { aT[j]=0.f; aP[j]=0.f; aTT[j]=0.f; aPP[j]=0.f; aTP[j]=0.f; }

    #pragma unroll
    for (int c = 0; c < C_CH; ++c) {
        #pragma unroll
        for (int dy = -1; dy <= 1; ++dy) {
            const int hh = h + dy;
            if ((unsigned)hh >= (unsigned)H_DIM) continue;  // zero-pad row (wave-uniform branch)
            const size_t base = ((size_t)((n * C_CH + c) * H_DIM + hh)) * W_DIM + w0;

            const float4 t0 = *reinterpret_cast<const float4*>(yt + base);
            const float4 t1 = *reinterpret_cast<const float4*>(yt + base + 4);
            const float4 p0 = *reinterpret_cast<const float4*>(yp + base);
            const float4 p1 = *reinterpret_cast<const float4*>(yp + base + 4);

            const float tv[8] = {t0.x, t0.y, t0.z, t0.w, t1.x, t1.y, t1.z, t1.w};
            const float pv[8] = {p0.x, p0.y, p0.z, p0.w, p1.x, p1.y, p1.z, p1.w};

            #pragma unroll
            for (int j = 0; j < 8; ++j) {
                const float t = tv[j], p = pv[j];
                aT[j]  += t;
                aP[j]  += p;
                aTT[j] = fmaf(t, t, aTT[j]);
                aPP[j] = fmaf(p, p, aPP[j]);
                aTP[j] = fmaf(t, p, aTP[j]);
            }
        }
    }

    // halo column sums: left halo (col w0-1) = prev lane's col 7 sums;
    // right halo (col w0+8) = next lane's col 0 sums. Zero at image edges.
    float lT  = __shfl_up(aT[7],  1);
    float lP  = __shfl_up(aP[7],  1);
    float lTT = __shfl_up(aTT[7], 1);
    float lPP = __shfl_up(aPP[7], 1);
    float lTP = __shfl_up(aTP[7], 1);
    float rT  = __shfl_down(aT[0],  1);
    float rP  = __shfl_down(aP[0],  1);
    float rTT = __shfl_down(aTT[0], 1);
    float rPP = __shfl_down(aPP[0], 1);
    float rTP = __shfl_down(aTP[0], 1);
    if (lane == 0)  { lT=0.f; lP=0.f; lTT=0.f; lPP=0.f; lTP=0.f; }
    if (lane == 63) { rT=0.f; rP=0.f; rTT=0.f; rPP=0.f; rTP=0.f; }

    const float C1f = 1.0e-4f;       // (0.01*1)^2
    const float C2f = 9.0e-4f;       // (0.03*1)^2
    const float inv_n = 1.f / 27.f;
    const float inv_v = 1.f / 26.f;

    float lsum = 0.f;
    #pragma unroll
    for (int k = 0; k < PXT; ++k) {
        const float st  = (k == 0 ? lT  : aT[k-1])  + aT[k]  + (k == 7 ? rT  : aT[k+1]);
        const float sp  = (k == 0 ? lP  : aP[k-1])  + aP[k]  + (k == 7 ? rP  : aP[k+1]);
        const float stt = (k == 0 ? lTT : aTT[k-1]) + aTT[k] + (k == 7 ? rTT : aTT[k+1]);
        const float spp = (k == 0 ? lPP : aPP[k-1]) + aPP[k] + (k == 7 ? rPP : aPP[k+1]);
        const float stp = (k == 0 ? lTP : aTP[k-1]) + aTP[k] + (k == 7 ? rTP : aTP[k+1]);

        const float ut = st * inv_n;
        const float up = sp * inv_n;
        const float vart = (stt - st * st * inv_n) * inv_v;
        const float varp = (spp - sp * sp * inv_n) * inv_v;
        const float cov  = stp * inv_n - ut * up;

        const float num = (2.f * ut * up + C1f) * (2.f * cov + C2f);
        const float den = (ut * ut + up * up + C1f) * (vart + varp + C2f);
        lsum = fmaf(-num * __builtin_amdgcn_rcpf(den), 0.5f, lsum + 0.5f);
    }

    // wave (64-lane) reduction
    #pragma unroll
    for (int off = 32; off > 0; off >>= 1)
        lsum += __shfl_down(lsum, off, 64);

    __shared__ float smem[BLOCK / 64];
    const int wl  = threadIdx.x & 63;
    const int wid = threadIdx.x >> 6;
    if (wl == 0) smem[wid] = lsum;
    __syncthreads();
    if (threadIdx.x == 0) {
        float s = 0.f;
        #pragma unroll
        for (int i = 0; i < BLOCK / 64; ++i) s += smem[i];
        atomicAdd(out, s * (1.f / (float)(N_IMG * H_DIM * W_DIM)));
    }
}

extern "C" void kernel_launch(void* const* d_in, const int* in_sizes, int n_in,
                              void* d_out, int out_size, void* d_ws, size_t ws_size,
                              hipStream_t stream) {
    const float* yp = (const float*)d_in[0];   // y_pred
    const float* yt = (const float*)d_in[1];   // y_true
    float* out = (float*)d_out;

    hipMemsetAsync(out, 0, sizeof(float) * (size_t)out_size, stream);

    const int grid = TOTAL_THREADS / BLOCK;    // 1024 blocks
    dssim_kernel<<<grid, BLOCK, 0, stream>>>(yp, yt, out);
}